// Round 23
// baseline (114.872 us; speedup 1.0000x reference)
//
#include <hip/hip_runtime.h>

// SigLoss: signature kernel PDE, loss = mean_a( K(X,X) + K(Y,Y) - 2 K(X,Y) ).
// A=256, L=256, D=32.
// R23: THREE PROBLEMS PER WAVE. R13-R22: every single-problem structure lands
// at ~400cyc/row with ~100cyc issue -> ~300cyc/row serial per-wave latency
// that in-order issue can't fill (<=1 wave/SIMD, nothing co-resident). Fix:
// fuse xx,yy,xy of the same `a` into ONE wave (256 blocks, 1 residency
// round). They share operands (A-sets: X,Y; B-sets: X,Y -> xy=A:X,B:Y), so
// per slot: 4 shared B ds_reads, 9 MFMAs, THREE independent interleaved
// scans (chains overlap: while xx's dep latency runs, yy/xy ops issue),
// 12 writes. LDS: B 64KB + xx single inc (R14 upfront-read discipline) +
// yy/xy static double buffers (R21 alias-free) = 145 KB -> 1 block/CU.

typedef _Float16 half8 __attribute__((ext_vector_type(8)));
typedef float f32x4_t __attribute__((ext_vector_type(4)));
typedef unsigned int u32x4 __attribute__((ext_vector_type(4)));

#define DPP_ADD(v, ctrl, rmask)                                               \
    ((v) + __int_as_float(__builtin_amdgcn_update_dpp(                        \
               0, __float_as_int(v), (ctrl), (rmask), 0xF, true)))

#define INV2048 4.8828125e-4f
#define BC8(x) __builtin_bit_cast(half8, x)

__global__ __launch_bounds__(64)
__attribute__((amdgpu_waves_per_eu(1, 1)))
void sig_pde(const float* __restrict__ X,
             const float* __restrict__ Y,
             float* __restrict__ partial) {
    const int a = blockIdx.x;                 // 256 blocks, one per `a`
    const float4* X4 = (const float4*)(X + (size_t)a * 8192);
    const float4* Y4 = (const float4*)(Y + (size_t)a * 8192);
    const int lane = threadIdx.x;
    const int m16 = lane & 15;
    const int g2 = (lane >> 4) * 2;

    __shared__ __attribute__((aligned(16))) u32x4 bHX[16 * 64];   // 16 KB
    __shared__ __attribute__((aligned(16))) u32x4 bLX[16 * 64];   // 16 KB
    __shared__ __attribute__((aligned(16))) u32x4 bHY[16 * 64];   // 16 KB
    __shared__ __attribute__((aligned(16))) u32x4 bLY[16 * 64];   // 16 KB
    __shared__ __attribute__((aligned(16))) float incXX[16 * 260];  // 16.25KB
    __shared__ __attribute__((aligned(16))) float incYYA[16 * 260];
    __shared__ __attribute__((aligned(16))) float incYYB[16 * 260];
    __shared__ __attribute__((aligned(16))) float incXYA[16 * 260];
    __shared__ __attribute__((aligned(16))) float incXYB[16 * 260];

    // ---- Stage B fragments for V = X and V = Y (R13 layout) ----
    auto stageB = [&](const float4* V4, u32x4* bH, u32x4* bL) {
#pragma unroll 2
        for (int t = 0; t < 16; ++t) {
            int col = t * 16 + m16;
            int cp = (col + 1 < 256) ? col + 1 : 255;   // col 255 -> dY=0
            float4 lo0 = V4[col * 8 + g2], lo1 = V4[col * 8 + g2 + 1];
            float4 hi0 = V4[cp * 8 + g2],  hi1 = V4[cp * 8 + g2 + 1];
            float d[8] = {hi0.x - lo0.x, hi0.y - lo0.y, hi0.z - lo0.z,
                          hi0.w - lo0.w, hi1.x - lo1.x, hi1.y - lo1.y,
                          hi1.z - lo1.z, hi1.w - lo1.w};
            half8 bh, bl;
#pragma unroll
            for (int i = 0; i < 8; ++i) {
                _Float16 h = (_Float16)d[i];
                bh[i] = h;
                bl[i] = (_Float16)((d[i] - (float)h) * 2048.0f);
            }
            bH[t * 64 + lane] = __builtin_bit_cast(u32x4, bh);
            bL[t * 64 + lane] = __builtin_bit_cast(u32x4, bl);
        }
    };
    stageB(X4, bHX, bLX);
    stageB(Y4, bHY, bLY);
    // single wave: same-wave DS ordering, no barrier needed

    // Three independent K-row states
    float kxx0 = 1.f, kxx1 = 1.f, kxx2 = 1.f, kxx3 = 1.f;
    float kyy0 = 1.f, kyy1 = 1.f, kyy2 = 1.f, kyy3 = 1.f;
    float kxy0 = 1.f, kxy1 = 1.f, kxy2 = 1.f, kxy3 = 1.f;

    auto loadA = [&](const float4* U4, int blk, float4 (&dst)[4]) {
        int r0 = blk * 16 + m16;
        int r1 = (r0 + 1 < 256) ? r0 + 1 : 255;   // dX[255] := 0 (unscanned)
        dst[0] = U4[r0 * 8 + g2];
        dst[1] = U4[r0 * 8 + g2 + 1];
        dst[2] = U4[r1 * 8 + g2];
        dst[3] = U4[r1 * 8 + g2 + 1];
    };
    auto makeAhAl = [&](const float4 (&src)[4], half8& ah, half8& al) {
        float d[8] = {src[2].x - src[0].x, src[2].y - src[0].y,
                      src[2].z - src[0].z, src[2].w - src[0].w,
                      src[3].x - src[1].x, src[3].y - src[1].y,
                      src[3].z - src[1].z, src[3].w - src[1].w};
#pragma unroll
        for (int i = 0; i < 8; ++i) {
            _Float16 h = (_Float16)d[i];
            ah[i] = h;
            al[i] = (_Float16)((d[i] - (float)h) * 2048.0f);
        }
    };

    auto scan_row = [&](float4 mv, float& kp0, float& kp1, float& kp2,
                        float& kp3) {
        float kn = __int_as_float(__builtin_amdgcn_update_dpp(
            0, __float_as_int(kp0), 0x130 /*wave_shl:1*/, 0xF, 0xF, true));
        float c0 = fmaf(kp0, mv.x, kp1);
        float c1 = fmaf(kp1, mv.y, kp2);
        float c2 = fmaf(kp2, mv.z, kp3);
        float c3 = (lane == 63) ? 0.0f : fmaf(kp3, mv.w, kn);
        float L0 = c0, L1 = L0 + c1, L2 = L1 + c2;
        float T = L2 + c3;
        float S = T;
        S = DPP_ADD(S, 0x111, 0xF);  // row_shr:1
        S = DPP_ADD(S, 0x112, 0xF);  // row_shr:2
        S = DPP_ADD(S, 0x114, 0xF);  // row_shr:4
        S = DPP_ADD(S, 0x118, 0xF);  // row_shr:8
        S = DPP_ADD(S, 0x142, 0xA);  // row_bcast:15 -> rows 1,3
        S = DPP_ADD(S, 0x143, 0xC);  // row_bcast:31 -> rows 2,3
        float E = S - T;
        kp0 = 1.0f + E;
        kp1 = 1.0f + E + L0;
        kp2 = 1.0f + E + L1;
        kp3 = 1.0f + E + L2;
    };

    const f32x4_t zero4 = {0.0f, 0.0f, 0.0f, 0.0f};
    const f32x4_t mone4 = {-1.0f, -1.0f, -1.0f, -1.0f};
    const int rb = (lane >> 4) << 2;

    auto comb_write = [&](float* __restrict__ wb, int k, f32x4_t a2,
                          f32x4_t a1) {
        int cc = k * 16 + m16;
        wb[(rb + 0) * 260 + cc] = fmaf(a2[0], INV2048, a1[0]);
        wb[(rb + 1) * 260 + cc] = fmaf(a2[1], INV2048, a1[1]);
        wb[(rb + 2) * 260 + cc] = fmaf(a2[2], INV2048, a1[2]);
        wb[(rb + 3) * 260 + cc] = fmaf(a2[3], INV2048, a1[3]);
    };

    float4 AX[4], AY[4];
    half8 ahX, alX, ahY, alY;
    loadA(X4, 0, AX);
    loadA(Y4, 0, AY);

    // ---- Phase 0: produce block 0 for all three problems ----
    makeAhAl(AX, ahX, alX);
    makeAhAl(AY, ahY, alY);
    loadA(X4, 1, AX);
    loadA(Y4, 1, AY);
#pragma unroll
    for (int k = 0; k < 16; ++k) {
        half8 bhx = BC8(bHX[k * 64 + lane]), blx = BC8(bLX[k * 64 + lane]);
        half8 bhy = BC8(bHY[k * 64 + lane]), bly = BC8(bLY[k * 64 + lane]);
        f32x4_t a2, a1;
        a2 = __builtin_amdgcn_mfma_f32_16x16x32_f16(ahX, blx, zero4, 0, 0, 0);
        a2 = __builtin_amdgcn_mfma_f32_16x16x32_f16(alX, bhx, a2, 0, 0, 0);
        a1 = __builtin_amdgcn_mfma_f32_16x16x32_f16(ahX, bhx, mone4, 0, 0, 0);
        comb_write(incXX, k, a2, a1);
        a2 = __builtin_amdgcn_mfma_f32_16x16x32_f16(ahY, bly, zero4, 0, 0, 0);
        a2 = __builtin_amdgcn_mfma_f32_16x16x32_f16(alY, bhy, a2, 0, 0, 0);
        a1 = __builtin_amdgcn_mfma_f32_16x16x32_f16(ahY, bhy, mone4, 0, 0, 0);
        comb_write(incYYA, k, a2, a1);
        a2 = __builtin_amdgcn_mfma_f32_16x16x32_f16(ahX, bly, zero4, 0, 0, 0);
        a2 = __builtin_amdgcn_mfma_f32_16x16x32_f16(alX, bhy, a2, 0, 0, 0);
        a1 = __builtin_amdgcn_mfma_f32_16x16x32_f16(ahX, bhy, mone4, 0, 0, 0);
        comb_write(incXYA, k, a2, a1);
    }

    // ---- Phase: produce block b (all 3) while scanning block b-1 (all 3).
    // xx: single buffer, ALL 16 rows read upfront (before any write - R14
    // discipline, same-wave DS order). yy/xy: static double buffers, rolling
    // lookahead-2 reads (rd/wr are distinct static arrays - R21).
    auto phase = [&](int b, const float* __restrict__ rdYY,
                     float* __restrict__ wrYY,
                     const float* __restrict__ rdXY,
                     float* __restrict__ wrXY) {
        makeAhAl(AX, ahX, alX);
        makeAhAl(AY, ahY, alY);
        if (b + 1 < 16) {
            loadA(X4, b + 1, AX);
            loadA(Y4, b + 1, AY);
        }
        const float4* rx = (const float4*)incXX;
        float4 wx[16];
#pragma unroll
        for (int r = 0; r < 16; ++r) wx[r] = rx[r * 65 + lane];
        const float4* ry = (const float4*)rdYY;
        const float4* rz = (const float4*)rdXY;
        float4 wy0 = ry[0 * 65 + lane], wy1 = ry[1 * 65 + lane];
        float4 wz0 = rz[0 * 65 + lane], wz1 = rz[1 * 65 + lane];
#pragma unroll
        for (int k = 0; k < 16; ++k) {
            half8 bhx = BC8(bHX[k * 64 + lane]), blx = BC8(bLX[k * 64 + lane]);
            half8 bhy = BC8(bHY[k * 64 + lane]), bly = BC8(bLY[k * 64 + lane]);
            f32x4_t xx2 = __builtin_amdgcn_mfma_f32_16x16x32_f16(
                ahX, blx, zero4, 0, 0, 0);
            xx2 = __builtin_amdgcn_mfma_f32_16x16x32_f16(alX, bhx, xx2, 0, 0, 0);
            f32x4_t xx1 = __builtin_amdgcn_mfma_f32_16x16x32_f16(
                ahX, bhx, mone4, 0, 0, 0);
            f32x4_t yy2 = __builtin_amdgcn_mfma_f32_16x16x32_f16(
                ahY, bly, zero4, 0, 0, 0);
            yy2 = __builtin_amdgcn_mfma_f32_16x16x32_f16(alY, bhy, yy2, 0, 0, 0);
            f32x4_t yy1 = __builtin_amdgcn_mfma_f32_16x16x32_f16(
                ahY, bhy, mone4, 0, 0, 0);
            f32x4_t zz2 = __builtin_amdgcn_mfma_f32_16x16x32_f16(
                ahX, bly, zero4, 0, 0, 0);
            zz2 = __builtin_amdgcn_mfma_f32_16x16x32_f16(alX, bhy, zz2, 0, 0, 0);
            f32x4_t zz1 = __builtin_amdgcn_mfma_f32_16x16x32_f16(
                ahX, bhy, mone4, 0, 0, 0);
            // three interleaved scans fill each other's dep stalls + MFMA shadow
            scan_row(wx[k], kxx0, kxx1, kxx2, kxx3);
            scan_row((k & 1) ? wy1 : wy0, kyy0, kyy1, kyy2, kyy3);
            scan_row((k & 1) ? wz1 : wz0, kxy0, kxy1, kxy2, kxy3);
            if (k + 2 < 16) {
                if (k & 1) { wy1 = ry[(k + 2) * 65 + lane];
                             wz1 = rz[(k + 2) * 65 + lane]; }
                else       { wy0 = ry[(k + 2) * 65 + lane];
                             wz0 = rz[(k + 2) * 65 + lane]; }
            }
            comb_write(incXX, k, xx2, xx1);
            comb_write(wrYY, k, yy2, yy1);
            comb_write(wrXY, k, zz2, zz1);
        }
    };

#pragma clang loop unroll(disable)
    for (int bb = 0; bb < 7; ++bb) {
        phase(2 * bb + 1, incYYA, incYYB, incXYA, incXYB);
        phase(2 * bb + 2, incYYB, incYYA, incXYB, incXYA);
    }
    phase(15, incYYA, incYYB, incXYA, incXYB);

    // ---- Tail: scan block 15, rows 0..14 (inc row 255 doesn't exist) ----
    {
        const float4* rx = (const float4*)incXX;
        const float4* ry = (const float4*)incYYB;
        const float4* rz = (const float4*)incXYB;
        float4 wx0 = rx[0 * 65 + lane], wx1 = rx[1 * 65 + lane];
        float4 wy0 = ry[0 * 65 + lane], wy1 = ry[1 * 65 + lane];
        float4 wz0 = rz[0 * 65 + lane], wz1 = rz[1 * 65 + lane];
#pragma unroll
        for (int k = 0; k < 15; ++k) {
            scan_row((k & 1) ? wx1 : wx0, kxx0, kxx1, kxx2, kxx3);
            scan_row((k & 1) ? wy1 : wy0, kyy0, kyy1, kyy2, kyy3);
            scan_row((k & 1) ? wz1 : wz0, kxy0, kxy1, kxy2, kxy3);
            if (k + 2 < 15) {
                if (k & 1) { wx1 = rx[(k + 2) * 65 + lane];
                             wy1 = ry[(k + 2) * 65 + lane];
                             wz1 = rz[(k + 2) * 65 + lane]; }
                else       { wx0 = rx[(k + 2) * 65 + lane];
                             wy0 = ry[(k + 2) * 65 + lane];
                             wz0 = rz[(k + 2) * 65 + lane]; }
            }
        }
    }

    if (lane == 63) {
        partial[a]       = kxx3;            // K_xx[255][255]
        partial[256 + a] = kyy3;            // K_yy[255][255]
        partial[512 + a] = -2.0f * kxy3;    // -2 K_xy[255][255]
    }
}

__global__ __launch_bounds__(256) void sig_reduce(const float* __restrict__ partial,
                                                  float* __restrict__ out) {
    const int t = threadIdx.x;
    float v = partial[t] + partial[t + 256] + partial[t + 512];
#pragma unroll
    for (int ofs = 32; ofs > 0; ofs >>= 1) v += __shfl_down(v, ofs);
    __shared__ float ws[4];
    if ((t & 63) == 0) ws[t >> 6] = v;
    __syncthreads();
    if (t == 0) out[0] = (ws[0] + ws[1] + ws[2] + ws[3]) * (1.0f / 256.0f);
}

extern "C" void kernel_launch(void* const* d_in, const int* in_sizes, int n_in,
                              void* d_out, int out_size, void* d_ws, size_t ws_size,
                              hipStream_t stream) {
    const float* X = (const float*)d_in[0];
    const float* Y = (const float*)d_in[1];
    float* partial = (float*)d_ws;       // 768 floats
    sig_pde<<<dim3(256), dim3(64), 0, stream>>>(X, Y, partial);
    sig_reduce<<<dim3(1), dim3(256), 0, stream>>>(partial, (float*)d_out);
}

// Round 24
// 58.531 us; speedup vs baseline: 1.9626x; 1.9626x over previous
//
#include <hip/hip_runtime.h>

// SigLoss: signature kernel PDE, loss = mean_a( K(X,X) + K(Y,Y) - 2 K(X,Y) ).
// A=256, L=256, D=32. One 64-lane wave per (pair,a) problem.
// R24 = R13's computation with ALL HOT LOOPS ROLLED (i-cache hypothesis).
// R13-R22 falsified every data-side stall theory; the one property shared by
// all ~43us variants: fully-unrolled 16-row phases -> hot bodies ~10-15KB.
// At 0.75 waves/SIMD nothing hides instruction-fetch stalls; a rolled body
// (~1.5KB total hot code) streams from L1I. LDS B-frags (rolled tile loop
// can't index reg arrays), single inc buffer (scan16(b-1) precedes tile
// writes(b) in program order -> same-wave DS order keeps it race-free).
// LDS 48.6KB -> 3 WG/CU -> all 768 waves resident.

typedef _Float16 half8 __attribute__((ext_vector_type(8)));
typedef float f32x4_t __attribute__((ext_vector_type(4)));
typedef unsigned int u32x4 __attribute__((ext_vector_type(4)));

#define DPP_ADD(v, ctrl, rmask)                                               \
    ((v) + __int_as_float(__builtin_amdgcn_update_dpp(                        \
               0, __float_as_int(v), (ctrl), (rmask), 0xF, true)))

#define INV2048 4.8828125e-4f
#define BC8(x) __builtin_bit_cast(half8, x)

__global__ __launch_bounds__(64)
__attribute__((amdgpu_waves_per_eu(1, 1)))
void sig_pde(const float* __restrict__ X,
             const float* __restrict__ Y,
             float* __restrict__ partial) {
    const int bid = blockIdx.x;
    const int p = bid >> 8;          // 0=xx, 1=yy, 2=xy
    const int a = bid & 255;
    const float* __restrict__ U = (p == 1) ? Y : X;   // rows (i)
    const float* __restrict__ V = (p == 0) ? X : Y;   // cols (j)
    U += (size_t)a * 256 * 32;
    V += (size_t)a * 256 * 32;
    const int lane = threadIdx.x;
    const int m16 = lane & 15;
    const int g2 = (lane >> 4) * 2;

    __shared__ __attribute__((aligned(16))) u32x4 bH[16 * 64];   // 16 KB
    __shared__ __attribute__((aligned(16))) u32x4 bL[16 * 64];   // 16 KB
    __shared__ __attribute__((aligned(16))) float incL[16 * 260]; // 16.6 KB

    const float4* U4 = (const float4*)U;
    const float4* V4 = (const float4*)V;

    // ---- Stage B fragments: dY[n][k] hi/lo (R13 layout) ----
#pragma unroll 2
    for (int t = 0; t < 16; ++t) {
        int col = t * 16 + m16;
        int cp = (col + 1 < 256) ? col + 1 : 255;   // col 255 clamps -> dY=0
        float4 lo0 = V4[col * 8 + g2], lo1 = V4[col * 8 + g2 + 1];
        float4 hi0 = V4[cp * 8 + g2],  hi1 = V4[cp * 8 + g2 + 1];
        float d[8] = {hi0.x - lo0.x, hi0.y - lo0.y, hi0.z - lo0.z, hi0.w - lo0.w,
                      hi1.x - lo1.x, hi1.y - lo1.y, hi1.z - lo1.z, hi1.w - lo1.w};
        half8 bh, bl;
#pragma unroll
        for (int i = 0; i < 8; ++i) {
            _Float16 h = (_Float16)d[i];
            bh[i] = h;
            bl[i] = (_Float16)((d[i] - (float)h) * 2048.0f);
        }
        bH[t * 64 + lane] = __builtin_bit_cast(u32x4, bh);
        bL[t * 64 + lane] = __builtin_bit_cast(u32x4, bl);
    }
    // single wave: same-wave DS ordering, no barrier needed

    // K row state
    float kp0 = 1.0f, kp1 = 1.0f, kp2 = 1.0f, kp3 = 1.0f;

    auto loadA = [&](int blk, float4 (&dst)[4]) {
        int r0 = blk * 16 + m16;
        int r1 = (r0 + 1 < 256) ? r0 + 1 : 255;   // dX[255] := 0 (unscanned)
        dst[0] = U4[r0 * 8 + g2];
        dst[1] = U4[r0 * 8 + g2 + 1];
        dst[2] = U4[r1 * 8 + g2];
        dst[3] = U4[r1 * 8 + g2 + 1];
    };
    auto makeAhAl = [&](const float4 (&src)[4], half8& ah, half8& al) {
        float d[8] = {src[2].x - src[0].x, src[2].y - src[0].y,
                      src[2].z - src[0].z, src[2].w - src[0].w,
                      src[3].x - src[1].x, src[3].y - src[1].y,
                      src[3].z - src[1].z, src[3].w - src[1].w};
#pragma unroll
        for (int i = 0; i < 8; ++i) {
            _Float16 h = (_Float16)d[i];
            ah[i] = h;
            al[i] = (_Float16)((d[i] - (float)h) * 2048.0f);
        }
    };

    auto scan_row = [&](float4 mv) {
        float kn = __int_as_float(__builtin_amdgcn_update_dpp(
            0, __float_as_int(kp0), 0x130 /*wave_shl:1*/, 0xF, 0xF, true));
        float c0 = fmaf(kp0, mv.x, kp1);
        float c1 = fmaf(kp1, mv.y, kp2);
        float c2 = fmaf(kp2, mv.z, kp3);
        float c3 = (lane == 63) ? 0.0f : fmaf(kp3, mv.w, kn);
        float L0 = c0, L1 = L0 + c1, L2 = L1 + c2;
        float T = L2 + c3;
        float S = T;
        S = DPP_ADD(S, 0x111, 0xF);  // row_shr:1
        S = DPP_ADD(S, 0x112, 0xF);  // row_shr:2
        S = DPP_ADD(S, 0x114, 0xF);  // row_shr:4
        S = DPP_ADD(S, 0x118, 0xF);  // row_shr:8
        S = DPP_ADD(S, 0x142, 0xA);  // row_bcast:15 -> rows 1,3
        S = DPP_ADD(S, 0x143, 0xC);  // row_bcast:31 -> rows 2,3
        float E = S - T;
        kp0 = 1.0f + E;
        kp1 = 1.0f + E + L0;
        kp2 = 1.0f + E + L1;
        kp3 = 1.0f + E + L2;
    };

    // Rolled 16-row scan: 2 rows/iter, named 2-ahead prefetch (tiny body).
    auto scan16 = [&](bool full) {
        const float4* rp = (const float4*)incL;   // 65 float4 per row
        float4 eA = rp[0 * 65 + lane], eB = rp[1 * 65 + lane];
#pragma clang loop unroll(disable)
        for (int j = 0; j < 7; ++j) {
            float4 nA = rp[(2 * j + 2) * 65 + lane];
            float4 nB = rp[(2 * j + 3) * 65 + lane];
            scan_row(eA);
            scan_row(eB);
            eA = nA; eB = nB;
        }
        scan_row(eA);                // row 14
        if (full) scan_row(eB);      // row 15 (absent for block 15)
    };

    const f32x4_t zero4 = {0.0f, 0.0f, 0.0f, 0.0f};
    const f32x4_t mone4 = {-1.0f, -1.0f, -1.0f, -1.0f};
    const int rb = (lane >> 4) << 2;

    // Rolled 16-tile MFMA block (B-frags from LDS, runtime t).
    auto mfma_block16 = [&](const half8& ah, const half8& al) {
#pragma clang loop unroll(disable)
        for (int t = 0; t < 16; ++t) {
            half8 bh = BC8(bH[t * 64 + lane]);
            half8 bl = BC8(bL[t * 64 + lane]);
            f32x4_t a2 = __builtin_amdgcn_mfma_f32_16x16x32_f16(
                ah, bl, zero4, 0, 0, 0);
            a2 = __builtin_amdgcn_mfma_f32_16x16x32_f16(al, bh, a2, 0, 0, 0);
            f32x4_t a1 = __builtin_amdgcn_mfma_f32_16x16x32_f16(
                ah, bh, mone4, 0, 0, 0);
            int cc = t * 16 + m16;
            incL[(rb + 0) * 260 + cc] = fmaf(a2[0], INV2048, a1[0]);
            incL[(rb + 1) * 260 + cc] = fmaf(a2[1], INV2048, a1[1]);
            incL[(rb + 2) * 260 + cc] = fmaf(a2[2], INV2048, a1[2]);
            incL[(rb + 3) * 260 + cc] = fmaf(a2[3], INV2048, a1[3]);
        }
    };

    // ---- Main pipeline (outer loop rolled too) ----
    float4 A[4];
    half8 ah, al;
    loadA(0, A);
    makeAhAl(A, ah, al);
    mfma_block16(ah, al);            // block 0
#pragma clang loop unroll(disable)
    for (int b = 1; b < 16; ++b) {
        loadA(b, A);                 // global loads hide under scan16
        scan16(true);                // scan block b-1 (reads precede writes)
        makeAhAl(A, ah, al);
        mfma_block16(ah, al);        // produce block b
    }
    scan16(false);                   // block 15: 15 rows (inc row 255 n/a)

    if (lane == 63) {
        // kp3 = K[255][255]
        partial[bid] = (p == 2 ? -2.0f : 1.0f) * kp3;
    }
}

__global__ __launch_bounds__(256) void sig_reduce(const float* __restrict__ partial,
                                                  float* __restrict__ out) {
    const int t = threadIdx.x;
    float v = partial[t] + partial[t + 256] + partial[t + 512];
#pragma unroll
    for (int ofs = 32; ofs > 0; ofs >>= 1) v += __shfl_down(v, ofs);
    __shared__ float ws[4];
    if ((t & 63) == 0) ws[t >> 6] = v;
    __syncthreads();
    if (t == 0) out[0] = (ws[0] + ws[1] + ws[2] + ws[3]) * (1.0f / 256.0f);
}

extern "C" void kernel_launch(void* const* d_in, const int* in_sizes, int n_in,
                              void* d_out, int out_size, void* d_ws, size_t ws_size,
                              hipStream_t stream) {
    const float* X = (const float*)d_in[0];
    const float* Y = (const float*)d_in[1];
    float* partial = (float*)d_ws;       // 768 floats
    sig_pde<<<dim3(768), dim3(64), 0, stream>>>(X, Y, partial);
    sig_reduce<<<dim3(1), dim3(256), 0, stream>>>(partial, (float*)d_out);
}